// Round 16
// baseline (5135.698 us; speedup 1.0000x reference)
//
#include <hip/hip_runtime.h>

typedef short bf16x8 __attribute__((ext_vector_type(8)));
typedef float f32x4  __attribute__((ext_vector_type(4)));
typedef unsigned long long u64;

#define MFMA16(a, b, c) __builtin_amdgcn_mfma_f32_16x16x32_bf16((a), (b), (c), 0, 0, 0)
#define AT_LD(p, o)    __hip_atomic_load((p), (o), __HIP_MEMORY_SCOPE_AGENT)
#define AT_ST(p, v, o) __hip_atomic_store((p), (v), (o), __HIP_MEMORY_SCOPE_AGENT)
#define AT_ADD(p, v, o) __hip_atomic_fetch_add((p), (v), (o), __HIP_MEMORY_SCOPE_AGENT)

#define HSLOT 67584      // h ring slot stride in bf16 elems (128KB + 4KB pad)

// barrier zone (words): chain c wave-flags at c*16384 + (wg*2+mtile)*64  (c=0..3)
// gemm cnt 65536, gemm gen 65600, gemm_done 65664, rec_done[c] 65728+c*64
__device__ __forceinline__ unsigned short f2bf(float f) {
  union { float f; unsigned u; } v; v.f = f;
  unsigned u = v.u;
  u += 0x7fffu + ((u >> 16) & 1u);
  return (unsigned short)(u >> 16);
}
__device__ __forceinline__ float bf2f(unsigned short h) {
  union { unsigned u; float f; } v; v.u = ((unsigned)h) << 16;
  return v.f;
}
__device__ __forceinline__ float sigf(float x) { return 1.f / (1.f + __expf(-x)); }
__device__ __forceinline__ float tanh_(float x) {
  x = fminf(15.f, fmaxf(-15.f, x));
  float e = __expf(2.f * x);
  return (e - 1.f) / (e + 1.f);
}

// ---- per-chunk release barrier for the 128 GEMM wgs ----
__device__ __forceinline__ void gbar_gemm(unsigned* bar, unsigned target) {
  __syncthreads();
  if (threadIdx.x == 0) {
    unsigned arr = AT_ADD(bar + 65536, 1u, __ATOMIC_RELEASE);  // vmcnt drain + L2 wb
    if (arr == target * 128u - 1u) AT_ST(bar + 65600, target, __ATOMIC_RELEASE);
    while (AT_LD(bar + 65600, __ATOMIC_RELAXED) < target) __builtin_amdgcn_s_sleep(4);
    asm volatile("" ::: "memory");
  }
  __syncthreads();
}

// ---------------- weight conversion fp32 -> bf16 ----------------
__global__ void k_conv(const float* __restrict__ wih, const float* __restrict__ whh,
                       const float* __restrict__ wemb,
                       unsigned short* __restrict__ oih, unsigned short* __restrict__ ohh,
                       unsigned short* __restrict__ oemb) {
  const size_t NIH = (size_t)4096 * 512, NHH = (size_t)4096 * 1024;
  const size_t NE = (size_t)32000 * 512;
  size_t i0 = ((size_t)blockIdx.x * blockDim.x + threadIdx.x) * 4;
  size_t gs = (size_t)gridDim.x * blockDim.x * 4;
  for (size_t j = i0; j < NIH; j += gs) {
    float4 v = *(const float4*)(wih + j);
    uint2 pk;
    pk.x = (unsigned)f2bf(v.x) | ((unsigned)f2bf(v.y) << 16);
    pk.y = (unsigned)f2bf(v.z) | ((unsigned)f2bf(v.w) << 16);
    *(uint2*)(oih + j) = pk;
  }
  for (size_t j = i0; j < NHH; j += gs) {
    float4 v = *(const float4*)(whh + j);
    uint2 pk;
    pk.x = (unsigned)f2bf(v.x) | ((unsigned)f2bf(v.y) << 16);
    pk.y = (unsigned)f2bf(v.z) | ((unsigned)f2bf(v.w) << 16);
    *(uint2*)(ohh + j) = pk;
  }
  if (oemb)
    for (size_t j = i0; j < NE; j += gs) {
      float4 v = *(const float4*)(wemb + j);
      uint2 pk;
      pk.x = (unsigned)f2bf(v.x) | ((unsigned)f2bf(v.y) << 16);
      pk.y = (unsigned)f2bf(v.z) | ((unsigned)f2bf(v.w) << 16);
      *(uint2*)(oemb + j) = pk;
    }
}

// ---------------- lengths / selection index ----------------
__global__ void k_tsel(const int* __restrict__ x, int* __restrict__ tsel,
                       int* __restrict__ padsel) {
  int b = threadIdx.x >> 3, j = threadIdx.x & 7;
  int c = 0;
  for (int t = j * 64; t < j * 64 + 64; ++t) c += (x[b * 512 + t] != 1) ? 1 : 0;
  c += __shfl_xor(c, 1);
  c += __shfl_xor(c, 2);
  c += __shfl_xor(c, 4);
  if (j == 0) {
    int ts = (c - 1) & 511;                        // len==0 wraps to T-1
    tsel[b] = ts;
    padsel[b] = (x[b * 512 + ts] == 1) ? 1 : 0;
  }
}

// ---------------- final logits: [64,1024] @ [8,1024]^T + b ----------------
__global__ void k_logits(const float* __restrict__ finalb, const float* __restrict__ Wout,
                         const float* __restrict__ bout, float* __restrict__ out) {
  int tid = threadIdx.x;
  for (int e = tid; e < 512; e += 256) {
    int b = e >> 3, o = e & 7;
    const float* f = finalb + (size_t)b * 1024;
    const float* w = Wout + (size_t)o * 1024;
    float s = 0.f;
    for (int k = 0; k < 1024; ++k) s += f[k] * w[k];
    out[e] = s + bout[o];
  }
}

// ---------------- main kernel: 256 wgs x 512 thr = 128 rec + 128 GEMM ----------------
// Rec: 4 batch chains x 2 waves; per-wave direct flags (minimal hop chain).
struct SmemT {
  union {
    struct { unsigned short sW[32][1032]; } rec;     // W_hh slice, gate-interleaved rows
    struct { unsigned short A[128][72]; unsigned short Bt[256][72]; } g;
    struct { unsigned short zs[128][136]; } zst;
  } u;
  unsigned short pad_force_one_wg_per_cu[8192];      // -> ~82 KB: 1 wg/CU
};

__global__ __launch_bounds__(512, 1) void k_main(
    const int* __restrict__ x, const float* __restrict__ Wemb,
    const float* __restrict__ bih, const float* __restrict__ bhh,
    const unsigned short* __restrict__ Wihb, const unsigned short* __restrict__ Whhb,
    const unsigned short* __restrict__ wembb,
    unsigned short* __restrict__ hr, float* __restrict__ finalb,
    const int* __restrict__ tsel, const int* __restrict__ padsel,
    unsigned short* __restrict__ zxr, unsigned* __restrict__ bar, int chunkT,
    int nslot) {
  __shared__ SmemT smem;
  const int wg = blockIdx.x, tid = threadIdx.x;
  const int wave = tid >> 6, lane = tid & 63;
  const int l15 = lane & 15, lg = lane >> 4;
  unsigned* gemm_done = bar + 65664;
  const f32x4 fz = {0.f, 0.f, 0.f, 0.f};
  const int nChunks = 512 / chunkT;
  const size_t slotE = (size_t)chunkT * 64 * 4096;
  if (tid == 65535) smem.pad_force_one_wg_per_cu[0] = 0;

  if (wg < 128) {
    // ================= RECURRENT ROLE: 4 chains x 2 waves =================
    const int chain = wave >> 1;        // b-range chain*16 .. +15
    const int mtile = wave & 1;
    const int my_b = chain * 16 + l15;
    const int col_local = 2 * lg + mtile;
    const int cg = wg * 8 + col_local;  // global h column
    unsigned* chflags = bar + chain * 16384;
    unsigned* myflag  = chflags + (wg * 2 + mtile) * 64;
    unsigned* recdone = bar + 65728 + chain * 64;
    // each lane polls 4 of the chain's 256 wave-flags
    const unsigned* pf0 = chflags + (lane * 4 + 0) * 64;
    const unsigned* pf1 = chflags + (lane * 4 + 1) * 64;
    const unsigned* pf2 = chflags + (lane * 4 + 2) * 64;
    const unsigned* pf3 = chflags + (lane * 4 + 3) * 64;

    // sW fill (512 threads): rows gate-interleaved (row n<16 -> col 2*(n>>2); else odd)
    for (int e = tid; e < 32 * 64; e += 512) {
      int n = e >> 6, kq = (e & 63) << 4;
      int coll = (n < 16) ? 2 * (n >> 2) : 2 * ((n - 16) >> 2) + 1;
      int grow = (n & 3) * 1024 + wg * 8 + coll;
      *(uint4*)&smem.u.rec.sW[n][kq] = *(const uint4*)(Whhb + (size_t)grow * 1024 + kq);
      *(uint4*)&smem.u.rec.sW[n][kq + 8] =
          *(const uint4*)(Whhb + (size_t)grow * 1024 + kq + 8);
    }
    float biasv[4];
#pragma unroll
    for (int g = 0; g < 4; ++g) biasv[g] = bih[g * 1024 + cg] + bhh[g * 1024 + cg];
    const int my_tsel = tsel[my_b];
    const int my_pad = padsel[my_b];
    const size_t hwe = (size_t)chain * 16384 + (size_t)wg * 128 + (size_t)l15 * 8 + col_local;
    const size_t hre = (size_t)chain * 16384 + (size_t)lg * 128 + (size_t)l15 * 8;
    float cc = 0.f;

    // zero h slot 0 (128 KB total across wgs)
    {
      int e = wg * 512 + tid;
      if (e < 32768) AT_ST((unsigned*)hr + e, 0u, __ATOMIC_RELAXED);
    }
    __syncthreads();                    // drains all waves' zero-stores
    if (lane == 0) AT_ST(myflag, 1u, __ATOMIC_RELAXED);

    for (int ch = 0; ch < nChunks; ++ch) {
      const int t0 = ch * chunkT;
      const unsigned short* zxbase = zxr + (size_t)(ch % nslot) * slotE;

      // per-wave chunk gate + own acquire-inv (fresh zx + h-ring for THIS chain)
      if (lane == 0) {
        while (AT_LD(gemm_done, __ATOMIC_RELAXED) < (unsigned)(ch + 1))
          __builtin_amdgcn_s_sleep(2);
      }
      (void)AT_LD(gemm_done, __ATOMIC_ACQUIRE);
      asm volatile("" ::: "memory");

      union { uint2 u2; unsigned short s[4]; } vv;
      vv.u2 = *(const uint2*)(zxbase + (size_t)(0 * 64 + my_b) * 4096 + cg * 4);

      for (int tl = 0; tl < chunkT; ++tl) {
        const int t = t0 + tl;
        const unsigned need = (unsigned)t + 1u;

        // ---- direct poll: all 256 wave-flags of this chain (4/lane) ----
        for (;;) {
          int ok = (AT_LD(pf0, __ATOMIC_RELAXED) >= need) &&
                   (AT_LD(pf1, __ATOMIC_RELAXED) >= need) &&
                   (AT_LD(pf2, __ATOMIC_RELAXED) >= need) &&
                   (AT_LD(pf3, __ATOMIC_RELAXED) >= need);
          if (__all(ok)) break;
          __builtin_amdgcn_s_sleep(1);
        }
        asm volatile("" ::: "memory");

        // ---- z = W_mtile @ h_chain : 32 MFMAs, K=1024 ----
        const unsigned short* hp = hr + (size_t)(t & 15) * HSLOT + hre;
        f32x4 r0 = fz;
        bf16x8 hf[32];
#pragma unroll
        for (int ks = 0; ks < 32; ++ks) hf[ks] = *(const bf16x8*)(hp + (size_t)ks * 512);
#pragma unroll
        for (int ks = 0; ks < 32; ++ks) {
          bf16x8 a0 = *(const bf16x8*)&smem.u.rec.sW[mtile * 16 + l15][ks * 32 + (lg << 3)];
          r0 = MFMA16(a0, hf[ks], r0);
        }

        // ---- gates lane-local: r0 = (i,f,g,o) for (my_b, cg) ----
        float z0 = r0[0] + biasv[0] + bf2f(vv.s[0]);
        float z1 = r0[1] + biasv[1] + bf2f(vv.s[1]);
        float z2 = r0[2] + biasv[2] + bf2f(vv.s[2]);
        float z3 = r0[3] + biasv[3] + bf2f(vv.s[3]);
        cc = sigf(z1) * cc + sigf(z0) * tanh_(z2);
        float h = sigf(z3) * tanh_(cc);

        if (t == my_tsel) finalb[(size_t)my_b * 1024 + cg] = my_pad ? 0.f : h;
        __hip_atomic_store(hr + (size_t)((t + 1) & 15) * HSLOT + hwe, f2bf(h),
                           __ATOMIC_RELAXED, __HIP_MEMORY_SCOPE_AGENT);

        asm volatile("s_waitcnt vmcnt(0)" ::: "memory");   // h (+finalb) store ack'd
        if (lane == 0) AT_ST(myflag, need + 1u, __ATOMIC_RELAXED);

        if (tl + 1 < chunkT) {          // prefetch next step's zx (off critical path)
          vv.u2 = *(const uint2*)(zxbase + (size_t)((tl + 1) * 64 + my_b) * 4096 + cg * 4);
        }
      }
      if (mtile == 0 && lane == 0) AT_ST(recdone, (unsigned)(ch + 1), __ATOMIC_RELAXED);
    }
  } else {
    // ============ GEMM ROLE (512 thr; tid&255 duplication — benign) ============
    const int gw = wg - 128;
    const int t2 = tid & 255;
    const int wv4 = (tid >> 6) & 3;
    unsigned gt = 0;
    for (int ch = 0; ch < nChunks; ++ch) {
      if (tid == 0 && ch >= nslot) {
        unsigned tgt = (unsigned)(ch - nslot + 1);
        for (;;) {
          unsigned a = AT_LD(bar + 65728, __ATOMIC_RELAXED);
          unsigned b = AT_LD(bar + 65792, __ATOMIC_RELAXED);
          unsigned c = AT_LD(bar + 65856, __ATOMIC_RELAXED);
          unsigned d = AT_LD(bar + 65920, __ATOMIC_RELAXED);
          if (a >= tgt && b >= tgt && c >= tgt && d >= tgt) break;
          __builtin_amdgcn_s_sleep(8);
        }
        asm volatile("" ::: "memory");
      }
      __syncthreads();
      const int t0 = ch * chunkT;
      unsigned short* zx = zxr + (size_t)(ch % nslot) * slotE;
      const int pmN = chunkT >> 1;
      const int npatch = pmN * 16;
      for (int p = gw; p < npatch; p += 128) {
        const int pm = p % pmN;
        const int n0 = (p / pmN) * 256;
        f32x4 acc[8][4];
#pragma unroll
        for (int mt = 0; mt < 8; ++mt)
#pragma unroll
          for (int nt = 0; nt < 4; ++nt) acc[mt][nt] = fz;
        for (int kc = 0; kc < 512; kc += 64) {
          __syncthreads();
          {
            int r = t2 >> 1, half = (t2 & 1) << 5;
            int tl = pm * 2 + (r >> 6), b = r & 63;
            int erow = x[b * 512 + t0 + tl];
            if (wembb) {
              const unsigned short* srcp = wembb + (size_t)erow * 512 + kc + half;
#pragma unroll
              for (int j = 0; j < 32; j += 8)
                *(uint4*)&smem.u.g.A[r][half + j] = *(const uint4*)(srcp + j);
            } else {
              const float* srcp = Wemb + (size_t)erow * 512 + kc + half;
#pragma unroll
              for (int j = 0; j < 32; j += 4) {
                float4 v = *(const float4*)(srcp + j);
                uint2 pk;
                pk.x = (unsigned)f2bf(v.x) | ((unsigned)f2bf(v.y) << 16);
                pk.y = (unsigned)f2bf(v.z) | ((unsigned)f2bf(v.w) << 16);
                *(uint2*)&smem.u.g.A[r][half + j] = pk;
              }
            }
          }
          {
            int zcx = n0 + t2;
            int wrow = (zcx & 3) * 1024 + (zcx >> 2);
            const unsigned short* srcp = Wihb + (size_t)wrow * 512 + kc;
#pragma unroll
            for (int j = 0; j < 64; j += 8)
              *(uint4*)&smem.u.g.Bt[t2][j] = *(const uint4*)(srcp + j);
          }
          __syncthreads();
#pragma unroll
          for (int ks = 0; ks < 64; ks += 32) {
            bf16x8 af[8];
#pragma unroll
            for (int mt = 0; mt < 8; ++mt)
              af[mt] = *(const bf16x8*)&smem.u.g.A[mt * 16 + l15][ks + (lg << 3)];
#pragma unroll
            for (int nt = 0; nt < 4; ++nt) {
              bf16x8 bfr =
                  *(const bf16x8*)&smem.u.g.Bt[(wv4 * 4 + nt) * 16 + l15][ks + (lg << 3)];
#pragma unroll
              for (int mt = 0; mt < 8; ++mt)
                acc[mt][nt] = MFMA16(af[mt], bfr, acc[mt][nt]);
            }
          }
        }
#pragma unroll
        for (int h = 0; h < 2; ++h) {
          __syncthreads();
          if ((wv4 >> 1) == h) {
#pragma unroll
            for (int mt = 0; mt < 8; ++mt)
#pragma unroll
              for (int nt = 0; nt < 4; ++nt)
#pragma unroll
                for (int r = 0; r < 4; ++r)
                  smem.u.zst.zs[mt * 16 + (lg << 2) + r][(wv4 & 1) * 64 + nt * 16 + l15] =
                      f2bf(acc[mt][nt][r]);
          }
          __syncthreads();
          int m = t2 >> 1, qq = (t2 & 1) << 6;
          int tl2 = pm * 2 + (m >> 6), bb = m & 63;
          unsigned short* dst = zx + ((size_t)(tl2 * 64 + bb)) * 4096 + n0 + h * 128 + qq;
#pragma unroll
          for (int j = 0; j < 64; j += 8)
            *(uint4*)(dst + j) = *(const uint4*)&smem.u.zst.zs[m][qq + j];
        }
      }
      gbar_gemm(bar, ++gt);
      if (wg == 128 && tid == 0) AT_ST(gemm_done, gt, __ATOMIC_RELAXED);
    }
  }
}

extern "C" void kernel_launch(void* const* d_in, const int* in_sizes, int n_in,
                              void* d_out, int out_size, void* d_ws, size_t ws_size,
                              hipStream_t stream) {
  (void)in_sizes; (void)n_in; (void)out_size;
  const int*   x    = (const int*)  d_in[0];
  const float* Wemb = (const float*)d_in[1];
  const float* Wih  = (const float*)d_in[2];
  const float* Whh  = (const float*)d_in[3];
  const float* bih  = (const float*)d_in[4];
  const float* bhh  = (const float*)d_in[5];
  const float* Wout = (const float*)d_in[6];
  const float* bout = (const float*)d_in[7];
  float* out = (float*)d_out;
  char* ws = (char*)d_ws;

  constexpr size_t OFF_WIH = 0;
  constexpr size_t OFF_WHH = OFF_WIH + (size_t)4096 * 512 * 2;    //  4 MB
  constexpr size_t OFF_HR  = OFF_WHH + (size_t)4096 * 1024 * 2;   // +8 MB
  constexpr size_t OFF_FIN = OFF_HR + (size_t)16 * HSLOT * 2;     // +2.06 MB
  constexpr size_t OFF_TS  = OFF_FIN + (size_t)64 * 1024 * 4;     // +256 KB
  constexpr size_t OFF_PS  = OFF_TS + 4096;
  constexpr size_t OFF_BAR = OFF_PS + 4096;
  constexpr size_t BAR_SZ  = 266240;                              // 260 KB barrier zone
  constexpr size_t OFF_WEB = OFF_BAR + BAR_SZ;
  constexpr size_t WEB_SZ  = (size_t)32000 * 512 * 2;             // 32 MB
  constexpr size_t SLOT_SZ = (size_t)16 * 64 * 4096 * 2;          // 8 MB per chunk slot

  int chunkT = 16;
  bool wbf = true;
  int nslot = 2;
  if (OFF_WEB + WEB_SZ + 2 * SLOT_SZ <= ws_size) {
    nslot = (int)((ws_size - OFF_WEB - WEB_SZ) / SLOT_SZ);
    if (nslot > 32) nslot = 32;
  } else if (OFF_WEB + 2 * SLOT_SZ <= ws_size) {
    wbf = false;
    nslot = (int)((ws_size - OFF_WEB) / SLOT_SZ);
    if (nslot > 32) nslot = 32;
  } else {
    wbf = false;
    while (chunkT > 2 &&
           OFF_WEB + (size_t)2 * chunkT * 64 * 4096 * 2 > ws_size)
      chunkT >>= 1;
  }
  const size_t OFF_ZX = OFF_WEB + (wbf ? WEB_SZ : 0);

  unsigned short* wihb  = (unsigned short*)(ws + OFF_WIH);
  unsigned short* whhb  = (unsigned short*)(ws + OFF_WHH);
  unsigned short* hr    = (unsigned short*)(ws + OFF_HR);
  float* finalb         = (float*)(ws + OFF_FIN);
  int* tsel             = (int*)(ws + OFF_TS);
  int* padsel           = (int*)(ws + OFF_PS);
  unsigned* bar         = (unsigned*)(ws + OFF_BAR);
  unsigned short* wembb = wbf ? (unsigned short*)(ws + OFF_WEB) : (unsigned short*)nullptr;
  unsigned short* zxr   = (unsigned short*)(ws + OFF_ZX);

  hipMemsetAsync(ws + OFF_BAR, 0, BAR_SZ, stream);
  k_conv<<<2048, 256, 0, stream>>>(Wih, Whh, Wemb, wihb, whhb, wembb);
  k_tsel<<<1, 512, 0, stream>>>(x, tsel, padsel);
  k_main<<<256, 512, 0, stream>>>(x, Wemb, bih, bhh, wihb, whhb, wembb, hr, finalb,
                                  tsel, padsel, zxr, bar, chunkT, nslot);
  k_logits<<<1, 256, 0, stream>>>(finalb, Wout, bout, out);
}

// Round 17
// 3661.728 us; speedup vs baseline: 1.4025x; 1.4025x over previous
//
#include <hip/hip_runtime.h>

typedef short bf16x8 __attribute__((ext_vector_type(8)));
typedef float f32x4  __attribute__((ext_vector_type(4)));
typedef unsigned long long u64;

#define MFMA16(a, b, c) __builtin_amdgcn_mfma_f32_16x16x32_bf16((a), (b), (c), 0, 0, 0)
#define AT_LD(p, o)    __hip_atomic_load((p), (o), __HIP_MEMORY_SCOPE_AGENT)
#define AT_ST(p, v, o) __hip_atomic_store((p), (v), (o), __HIP_MEMORY_SCOPE_AGENT)
#define AT_ADD(p, v, o) __hip_atomic_fetch_add((p), (v), (o), __HIP_MEMORY_SCOPE_AGENT)
#define WG_LD(p) __hip_atomic_load((p), __ATOMIC_ACQUIRE, __HIP_MEMORY_SCOPE_WORKGROUP)
#define WG_ST(p, v) __hip_atomic_store((p), (v), __ATOMIC_RELEASE, __HIP_MEMORY_SCOPE_WORKGROUP)

#define HSLOT 67584      // h ring slot stride in bf16 elems (128KB + 4KB pad)

// bar layout (words): chain c wg-flags at c*8192 + wg*64 (c=0..3);
// gemm cnt 32768, gemm gen 32832, gemm_done 32896, rec_done[c] 32960+c*64
__device__ __forceinline__ unsigned short f2bf(float f) {
  union { float f; unsigned u; } v; v.f = f;
  unsigned u = v.u;
  u += 0x7fffu + ((u >> 16) & 1u);
  return (unsigned short)(u >> 16);
}
__device__ __forceinline__ float bf2f(unsigned short h) {
  union { unsigned u; float f; } v; v.u = ((unsigned)h) << 16;
  return v.f;
}
__device__ __forceinline__ float sigf(float x) { return 1.f / (1.f + __expf(-x)); }
__device__ __forceinline__ float tanh_(float x) {
  x = fminf(15.f, fmaxf(-15.f, x));
  float e = __expf(2.f * x);
  return (e - 1.f) / (e + 1.f);
}

// ---- per-chunk release barrier for the 128 GEMM wgs ----
__device__ __forceinline__ void gbar_gemm(unsigned* bar, unsigned target) {
  __syncthreads();
  if (threadIdx.x == 0) {
    unsigned arr = AT_ADD(bar + 32768, 1u, __ATOMIC_RELEASE);  // vmcnt drain + L2 wb
    if (arr == target * 128u - 1u) AT_ST(bar + 32832, target, __ATOMIC_RELEASE);
    while (AT_LD(bar + 32832, __ATOMIC_RELAXED) < target) __builtin_amdgcn_s_sleep(4);
    asm volatile("" ::: "memory");
  }
  __syncthreads();
}

// ---------------- weight conversion fp32 -> bf16 ----------------
__global__ void k_conv(const float* __restrict__ wih, const float* __restrict__ whh,
                       const float* __restrict__ wemb,
                       unsigned short* __restrict__ oih, unsigned short* __restrict__ ohh,
                       unsigned short* __restrict__ oemb) {
  const size_t NIH = (size_t)4096 * 512, NHH = (size_t)4096 * 1024;
  const size_t NE = (size_t)32000 * 512;
  size_t i0 = ((size_t)blockIdx.x * blockDim.x + threadIdx.x) * 4;
  size_t gs = (size_t)gridDim.x * blockDim.x * 4;
  for (size_t j = i0; j < NIH; j += gs) {
    float4 v = *(const float4*)(wih + j);
    uint2 pk;
    pk.x = (unsigned)f2bf(v.x) | ((unsigned)f2bf(v.y) << 16);
    pk.y = (unsigned)f2bf(v.z) | ((unsigned)f2bf(v.w) << 16);
    *(uint2*)(oih + j) = pk;
  }
  for (size_t j = i0; j < NHH; j += gs) {
    float4 v = *(const float4*)(whh + j);
    uint2 pk;
    pk.x = (unsigned)f2bf(v.x) | ((unsigned)f2bf(v.y) << 16);
    pk.y = (unsigned)f2bf(v.z) | ((unsigned)f2bf(v.w) << 16);
    *(uint2*)(ohh + j) = pk;
  }
  if (oemb)
    for (size_t j = i0; j < NE; j += gs) {
      float4 v = *(const float4*)(wemb + j);
      uint2 pk;
      pk.x = (unsigned)f2bf(v.x) | ((unsigned)f2bf(v.y) << 16);
      pk.y = (unsigned)f2bf(v.z) | ((unsigned)f2bf(v.w) << 16);
      *(uint2*)(oemb + j) = pk;
    }
}

// ---------------- lengths / selection index ----------------
__global__ void k_tsel(const int* __restrict__ x, int* __restrict__ tsel,
                       int* __restrict__ padsel) {
  int b = threadIdx.x >> 3, j = threadIdx.x & 7;
  int c = 0;
  for (int t = j * 64; t < j * 64 + 64; ++t) c += (x[b * 512 + t] != 1) ? 1 : 0;
  c += __shfl_xor(c, 1);
  c += __shfl_xor(c, 2);
  c += __shfl_xor(c, 4);
  if (j == 0) {
    int ts = (c - 1) & 511;                        // len==0 wraps to T-1
    tsel[b] = ts;
    padsel[b] = (x[b * 512 + ts] == 1) ? 1 : 0;
  }
}

// ---------------- final logits: [64,1024] @ [8,1024]^T + b ----------------
__global__ void k_logits(const float* __restrict__ finalb, const float* __restrict__ Wout,
                         const float* __restrict__ bout, float* __restrict__ out) {
  int tid = threadIdx.x;
  for (int e = tid; e < 512; e += 256) {
    int b = e >> 3, o = e & 7;
    const float* f = finalb + (size_t)b * 1024;
    const float* w = Wout + (size_t)o * 1024;
    float s = 0.f;
    for (int k = 0; k < 1024; ++k) s += f[k] * w[k];
    out[e] = s + bout[o];
  }
}

// ---------------- main kernel: 256 wgs x 512 thr = 128 rec + 128 GEMM ----------------
// Rec: 4 chains x 2 waves, R15-style relay (LDS cnt + per-wg-chain flag + poller + token).
struct SmemT {
  unsigned tok[4];                                   // per-chain consumer token
  unsigned cnt[4];                                   // per-chain producer counter
  union {
    struct { unsigned short sW[32][1032]; } rec;     // W_hh slice, gate-interleaved rows
    struct { unsigned short A[128][72]; unsigned short Bt[256][72]; } g;
    struct { unsigned short zs[128][136]; } zst;
  } u;
  unsigned short pad_force_one_wg_per_cu[8192];      // -> ~82 KB: 1 wg/CU
};

__global__ __launch_bounds__(512, 1) void k_main(
    const int* __restrict__ x, const float* __restrict__ Wemb,
    const float* __restrict__ bih, const float* __restrict__ bhh,
    const unsigned short* __restrict__ Wihb, const unsigned short* __restrict__ Whhb,
    const unsigned short* __restrict__ wembb,
    unsigned short* __restrict__ hr, float* __restrict__ finalb,
    const int* __restrict__ tsel, const int* __restrict__ padsel,
    unsigned short* __restrict__ zxr, unsigned* __restrict__ bar, int chunkT,
    int nslot) {
  __shared__ SmemT smem;
  const int wg = blockIdx.x, tid = threadIdx.x;
  const int wave = tid >> 6, lane = tid & 63;
  const int l15 = lane & 15, lg = lane >> 4;
  unsigned* gemm_done = bar + 32896;
  const f32x4 fz = {0.f, 0.f, 0.f, 0.f};
  const int nChunks = 512 / chunkT;
  const size_t slotE = (size_t)chunkT * 64 * 4096;
  if (tid == 65535) smem.pad_force_one_wg_per_cu[0] = 0;

  if (wg < 128) {
    // ================= RECURRENT ROLE: 4 chains x 2 waves =================
    const int chain = wave >> 1;        // b-range chain*16 .. +15
    const int mtile = wave & 1;         // column sub-tile; also poller if mtile==0
    const int my_b = chain * 16 + l15;
    const int col_local = 2 * lg + mtile;
    const int cg = wg * 8 + col_local;  // global h column
    unsigned* chflags = bar + chain * 8192;
    unsigned* myflag  = chflags + wg * 64;
    unsigned* recdone = bar + 32960 + chain * 64;
    const unsigned* pf0 = chflags + (lane * 2) * 64;
    const unsigned* pf1 = chflags + (lane * 2 + 1) * 64;

    if (tid < 4) { smem.tok[tid] = 0; smem.cnt[tid] = 0; }
    // sW fill (512 threads): rows gate-interleaved (row n<16 -> col 2*(n>>2); else odd)
    for (int e = tid; e < 32 * 64; e += 512) {
      int n = e >> 6, kq = (e & 63) << 4;
      int coll = (n < 16) ? 2 * (n >> 2) : 2 * ((n - 16) >> 2) + 1;
      int grow = (n & 3) * 1024 + wg * 8 + coll;
      *(uint4*)&smem.u.rec.sW[n][kq] = *(const uint4*)(Whhb + (size_t)grow * 1024 + kq);
      *(uint4*)&smem.u.rec.sW[n][kq + 8] =
          *(const uint4*)(Whhb + (size_t)grow * 1024 + kq + 8);
    }
    float biasv[4];
#pragma unroll
    for (int g = 0; g < 4; ++g) biasv[g] = bih[g * 1024 + cg] + bhh[g * 1024 + cg];
    const int my_tsel = tsel[my_b];
    const int my_pad = padsel[my_b];
    const size_t hwe = (size_t)chain * 16384 + (size_t)wg * 128 + (size_t)l15 * 8 + col_local;
    const size_t hre = (size_t)chain * 16384 + (size_t)lg * 128 + (size_t)l15 * 8;
    float cc = 0.f;

    // zero h slot 0 (128 KB total across wgs)
    {
      int e = wg * 512 + tid;
      if (e < 32768) AT_ST((unsigned*)hr + e, 0u, __ATOMIC_RELAXED);
    }
    __syncthreads();                    // drains all waves' zero-stores
    if (mtile == 0 && lane == 0) AT_ST(myflag, 1u, __ATOMIC_RELAXED);

    for (int ch = 0; ch < nChunks; ++ch) {
      const int t0 = ch * chunkT;
      const unsigned short* zxbase = zxr + (size_t)(ch % nslot) * slotE;

      // ALL waves gate on this chunk's zx publication; one acquire-inv each
      while (AT_LD(gemm_done, __ATOMIC_RELAXED) < (unsigned)(ch + 1))
        __builtin_amdgcn_s_sleep(2);
      (void)AT_LD(gemm_done, __ATOMIC_ACQUIRE);   // inv: fresh zx + h-ring refresh
      asm volatile("" ::: "memory");

      union { uint2 u2; unsigned short s[4]; } vv;
      vv.u2 = *(const uint2*)(zxbase + (size_t)my_b * 4096 + cg * 4);

      for (int tl = 0; tl < chunkT; ++tl) {
        const int t = t0 + tl;
        const unsigned need = (unsigned)t + 1u;

        // ---- wait: poller wave polls 128 chain flags (2/lane); partner spins token ----
        if (mtile == 0) {
          for (;;) {
            int ok = (AT_LD(pf0, __ATOMIC_RELAXED) >= need) &&
                     (AT_LD(pf1, __ATOMIC_RELAXED) >= need);
            if (__all(ok)) break;
            __builtin_amdgcn_s_sleep(1);
          }
          if (lane == 0) WG_ST(&smem.tok[chain], need);
        } else {
          while (WG_LD(&smem.tok[chain]) < need) __builtin_amdgcn_s_sleep(1);
        }
        asm volatile("" ::: "memory");

        // ---- z = W_mtile @ h_chain : 32 MFMAs, K=1024 ----
        const unsigned short* hp = hr + (size_t)(t & 15) * HSLOT + hre;
        f32x4 r0 = fz;
        bf16x8 hf[32];
#pragma unroll
        for (int ks = 0; ks < 32; ++ks) hf[ks] = *(const bf16x8*)(hp + (size_t)ks * 512);
#pragma unroll
        for (int ks = 0; ks < 32; ++ks) {
          bf16x8 a0 = *(const bf16x8*)&smem.u.rec.sW[mtile * 16 + l15][ks * 32 + (lg << 3)];
          r0 = MFMA16(a0, hf[ks], r0);
        }

        // ---- gates lane-local: r0 = (i,f,g,o) for (my_b, cg) ----
        float z0 = r0[0] + biasv[0] + bf2f(vv.s[0]);
        float z1 = r0[1] + biasv[1] + bf2f(vv.s[1]);
        float z2 = r0[2] + biasv[2] + bf2f(vv.s[2]);
        float z3 = r0[3] + biasv[3] + bf2f(vv.s[3]);
        cc = sigf(z1) * cc + sigf(z0) * tanh_(z2);
        float h = sigf(z3) * tanh_(cc);

        if (t == my_tsel) finalb[(size_t)my_b * 1024 + cg] = my_pad ? 0.f : h;
        __hip_atomic_store(hr + (size_t)((t + 1) & 15) * HSLOT + hwe, f2bf(h),
                           __ATOMIC_RELAXED, __HIP_MEMORY_SCOPE_AGENT);

        asm volatile("s_waitcnt vmcnt(0)" ::: "memory");   // h (+finalb) store ack'd
        if (lane == 0)
          __hip_atomic_fetch_add(&smem.cnt[chain], 1u, __ATOMIC_ACQ_REL,
                                 __HIP_MEMORY_SCOPE_WORKGROUP);
        if (mtile == 0 && lane == 0) {
          while (__hip_atomic_load(&smem.cnt[chain], __ATOMIC_ACQUIRE,
                                   __HIP_MEMORY_SCOPE_WORKGROUP) < 2u * need)
            __builtin_amdgcn_s_sleep(1);
          AT_ST(myflag, need + 1u, __ATOMIC_RELAXED);
        }

        if (tl + 1 < chunkT) {          // prefetch next step's zx (off producer path)
          vv.u2 = *(const uint2*)(zxbase + (size_t)((tl + 1) * 64 + my_b) * 4096 + cg * 4);
        }
      }
      if (mtile == 0 && lane == 0) AT_ST(recdone, (unsigned)(ch + 1), __ATOMIC_RELAXED);
    }
  } else {
    // ============ GEMM ROLE (512 thr; tid&255 duplication — benign) ============
    const int gw = wg - 128;
    const int t2 = tid & 255;
    const int wv4 = (tid >> 6) & 3;
    unsigned gt = 0;
    for (int ch = 0; ch < nChunks; ++ch) {
      if (tid == 0 && ch >= nslot) {
        unsigned tgt = (unsigned)(ch - nslot + 1);
        for (;;) {
          unsigned a = AT_LD(bar + 32960, __ATOMIC_RELAXED);
          unsigned b = AT_LD(bar + 33024, __ATOMIC_RELAXED);
          unsigned c = AT_LD(bar + 33088, __ATOMIC_RELAXED);
          unsigned d = AT_LD(bar + 33152, __ATOMIC_RELAXED);
          if (a >= tgt && b >= tgt && c >= tgt && d >= tgt) break;
          __builtin_amdgcn_s_sleep(8);
        }
        asm volatile("" ::: "memory");
      }
      __syncthreads();
      const int t0 = ch * chunkT;
      unsigned short* zx = zxr + (size_t)(ch % nslot) * slotE;
      const int pmN = chunkT >> 1;
      const int npatch = pmN * 16;
      for (int p = gw; p < npatch; p += 128) {
        const int pm = p % pmN;
        const int n0 = (p / pmN) * 256;
        f32x4 acc[8][4];
#pragma unroll
        for (int mt = 0; mt < 8; ++mt)
#pragma unroll
          for (int nt = 0; nt < 4; ++nt) acc[mt][nt] = fz;
        for (int kc = 0; kc < 512; kc += 64) {
          __syncthreads();
          {
            int r = t2 >> 1, half = (t2 & 1) << 5;
            int tl = pm * 2 + (r >> 6), b = r & 63;
            int erow = x[b * 512 + t0 + tl];
            if (wembb) {
              const unsigned short* srcp = wembb + (size_t)erow * 512 + kc + half;
#pragma unroll
              for (int j = 0; j < 32; j += 8)
                *(uint4*)&smem.u.g.A[r][half + j] = *(const uint4*)(srcp + j);
            } else {
              const float* srcp = Wemb + (size_t)erow * 512 + kc + half;
#pragma unroll
              for (int j = 0; j < 32; j += 4) {
                float4 v = *(const float4*)(srcp + j);
                uint2 pk;
                pk.x = (unsigned)f2bf(v.x) | ((unsigned)f2bf(v.y) << 16);
                pk.y = (unsigned)f2bf(v.z) | ((unsigned)f2bf(v.w) << 16);
                *(uint2*)&smem.u.g.A[r][half + j] = pk;
              }
            }
          }
          {
            int zcx = n0 + t2;
            int wrow = (zcx & 3) * 1024 + (zcx >> 2);
            const unsigned short* srcp = Wihb + (size_t)wrow * 512 + kc;
#pragma unroll
            for (int j = 0; j < 64; j += 8)
              *(uint4*)&smem.u.g.Bt[t2][j] = *(const uint4*)(srcp + j);
          }
          __syncthreads();
#pragma unroll
          for (int ks = 0; ks < 64; ks += 32) {
            bf16x8 af[8];
#pragma unroll
            for (int mt = 0; mt < 8; ++mt)
              af[mt] = *(const bf16x8*)&smem.u.g.A[mt * 16 + l15][ks + (lg << 3)];
#pragma unroll
            for (int nt = 0; nt < 4; ++nt) {
              bf16x8 bfr =
                  *(const bf16x8*)&smem.u.g.Bt[(wv4 * 4 + nt) * 16 + l15][ks + (lg << 3)];
#pragma unroll
              for (int mt = 0; mt < 8; ++mt)
                acc[mt][nt] = MFMA16(af[mt], bfr, acc[mt][nt]);
            }
          }
        }
#pragma unroll
        for (int h = 0; h < 2; ++h) {
          __syncthreads();
          if ((wv4 >> 1) == h) {
#pragma unroll
            for (int mt = 0; mt < 8; ++mt)
#pragma unroll
              for (int nt = 0; nt < 4; ++nt)
#pragma unroll
                for (int r = 0; r < 4; ++r)
                  smem.u.zst.zs[mt * 16 + (lg << 2) + r][(wv4 & 1) * 64 + nt * 16 + l15] =
                      f2bf(acc[mt][nt][r]);
          }
          __syncthreads();
          int m = t2 >> 1, qq = (t2 & 1) << 6;
          int tl2 = pm * 2 + (m >> 6), bb = m & 63;
          unsigned short* dst = zx + ((size_t)(tl2 * 64 + bb)) * 4096 + n0 + h * 128 + qq;
#pragma unroll
          for (int j = 0; j < 64; j += 8)
            *(uint4*)(dst + j) = *(const uint4*)&smem.u.zst.zs[m][qq + j];
        }
      }
      gbar_gemm(bar, ++gt);
      if (wg == 128 && tid == 0) AT_ST(gemm_done, gt, __ATOMIC_RELAXED);
    }
  }
}

extern "C" void kernel_launch(void* const* d_in, const int* in_sizes, int n_in,
                              void* d_out, int out_size, void* d_ws, size_t ws_size,
                              hipStream_t stream) {
  (void)in_sizes; (void)n_in; (void)out_size;
  const int*   x    = (const int*)  d_in[0];
  const float* Wemb = (const float*)d_in[1];
  const float* Wih  = (const float*)d_in[2];
  const float* Whh  = (const float*)d_in[3];
  const float* bih  = (const float*)d_in[4];
  const float* bhh  = (const float*)d_in[5];
  const float* Wout = (const float*)d_in[6];
  const float* bout = (const float*)d_in[7];
  float* out = (float*)d_out;
  char* ws = (char*)d_ws;

  constexpr size_t OFF_WIH = 0;
  constexpr size_t OFF_WHH = OFF_WIH + (size_t)4096 * 512 * 2;    //  4 MB
  constexpr size_t OFF_HR  = OFF_WHH + (size_t)4096 * 1024 * 2;   // +8 MB
  constexpr size_t OFF_FIN = OFF_HR + (size_t)16 * HSLOT * 2;     // +2.06 MB
  constexpr size_t OFF_TS  = OFF_FIN + (size_t)64 * 1024 * 4;     // +256 KB
  constexpr size_t OFF_PS  = OFF_TS + 4096;
  constexpr size_t OFF_BAR = OFF_PS + 4096;
  constexpr size_t BAR_SZ  = 139264;                              // 136 KB barrier zone
  constexpr size_t OFF_WEB = OFF_BAR + BAR_SZ;
  constexpr size_t WEB_SZ  = (size_t)32000 * 512 * 2;             // 32 MB
  constexpr size_t SLOT_SZ = (size_t)16 * 64 * 4096 * 2;          // 8 MB per chunk slot

  int chunkT = 16;
  bool wbf = true;
  int nslot = 2;
  if (OFF_WEB + WEB_SZ + 2 * SLOT_SZ <= ws_size) {
    nslot = (int)((ws_size - OFF_WEB - WEB_SZ) / SLOT_SZ);
    if (nslot > 32) nslot = 32;
  } else if (OFF_WEB + 2 * SLOT_SZ <= ws_size) {
    wbf = false;
    nslot = (int)((ws_size - OFF_WEB) / SLOT_SZ);
    if (nslot > 32) nslot = 32;
  } else {
    wbf = false;
    while (chunkT > 2 &&
           OFF_WEB + (size_t)2 * chunkT * 64 * 4096 * 2 > ws_size)
      chunkT >>= 1;
  }
  const size_t OFF_ZX = OFF_WEB + (wbf ? WEB_SZ : 0);

  unsigned short* wihb  = (unsigned short*)(ws + OFF_WIH);
  unsigned short* whhb  = (unsigned short*)(ws + OFF_WHH);
  unsigned short* hr    = (unsigned short*)(ws + OFF_HR);
  float* finalb         = (float*)(ws + OFF_FIN);
  int* tsel             = (int*)(ws + OFF_TS);
  int* padsel           = (int*)(ws + OFF_PS);
  unsigned* bar         = (unsigned*)(ws + OFF_BAR);
  unsigned short* wembb = wbf ? (unsigned short*)(ws + OFF_WEB) : (unsigned short*)nullptr;
  unsigned short* zxr   = (unsigned short*)(ws + OFF_ZX);

  hipMemsetAsync(ws + OFF_BAR, 0, BAR_SZ, stream);
  k_conv<<<2048, 256, 0, stream>>>(Wih, Whh, Wemb, wihb, whhb, wembb);
  k_tsel<<<1, 512, 0, stream>>>(x, tsel, padsel);
  k_main<<<256, 512, 0, stream>>>(x, Wemb, bih, bhh, wihb, whhb, wembb, hr, finalb,
                                  tsel, padsel, zxr, bar, chunkT, nslot);
  k_logits<<<1, 256, 0, stream>>>(finalb, Wout, bout, out);
}

// Round 18
// 2858.652 us; speedup vs baseline: 1.7965x; 1.2809x over previous
//
#include <hip/hip_runtime.h>

typedef short bf16x8 __attribute__((ext_vector_type(8)));
typedef float f32x4  __attribute__((ext_vector_type(4)));
typedef unsigned long long u64;

#define MFMA16(a, b, c) __builtin_amdgcn_mfma_f32_16x16x32_bf16((a), (b), (c), 0, 0, 0)
#define AT_LD(p, o)    __hip_atomic_load((p), (o), __HIP_MEMORY_SCOPE_AGENT)
#define AT_ST(p, v, o) __hip_atomic_store((p), (v), (o), __HIP_MEMORY_SCOPE_AGENT)
#define AT_ADD(p, v, o) __hip_atomic_fetch_add((p), (v), (o), __HIP_MEMORY_SCOPE_AGENT)
#define WG_LD(p) __hip_atomic_load((p), __ATOMIC_ACQUIRE, __HIP_MEMORY_SCOPE_WORKGROUP)
#define WG_ST(p, v) __hip_atomic_store((p), (v), __ATOMIC_RELEASE, __HIP_MEMORY_SCOPE_WORKGROUP)

#define HSLOT 67584      // h ring slot stride in bf16 elems (128KB + 4KB pad)

// barrier zone (words): chainA flags wg*64 (0..8128); chainB flags 8192+wg*64;
// gemm cnt 16512, gemm gen 16576, gemm_done 16640, rec_doneA 16704, rec_doneB 16768
__device__ __forceinline__ unsigned short f2bf(float f) {
  union { float f; unsigned u; } v; v.f = f;
  unsigned u = v.u;
  u += 0x7fffu + ((u >> 16) & 1u);
  return (unsigned short)(u >> 16);
}
__device__ __forceinline__ float bf2f(unsigned short h) {
  union { unsigned u; float f; } v; v.u = ((unsigned)h) << 16;
  return v.f;
}
__device__ __forceinline__ float sigf(float x) { return 1.f / (1.f + __expf(-x)); }
__device__ __forceinline__ float tanh_(float x) {
  x = fminf(15.f, fmaxf(-15.f, x));
  float e = __expf(2.f * x);
  return (e - 1.f) / (e + 1.f);
}

// ---- per-chunk release barrier for the 128 GEMM wgs ----
__device__ __forceinline__ void gbar_gemm(unsigned* bar, unsigned target) {
  __syncthreads();
  if (threadIdx.x == 0) {
    unsigned arr = AT_ADD(bar + 16512, 1u, __ATOMIC_RELEASE);  // vmcnt drain + L2 wb
    if (arr == target * 128u - 1u) AT_ST(bar + 16576, target, __ATOMIC_RELEASE);
    while (AT_LD(bar + 16576, __ATOMIC_RELAXED) < target) __builtin_amdgcn_s_sleep(4);
    asm volatile("" ::: "memory");
  }
  __syncthreads();
}

// ---------------- weight conversion fp32 -> bf16 ----------------
__global__ void k_conv(const float* __restrict__ wih, const float* __restrict__ whh,
                       const float* __restrict__ wemb,
                       unsigned short* __restrict__ oih, unsigned short* __restrict__ ohh,
                       unsigned short* __restrict__ oemb) {
  const size_t NIH = (size_t)4096 * 512, NHH = (size_t)4096 * 1024;
  const size_t NE = (size_t)32000 * 512;
  size_t i0 = ((size_t)blockIdx.x * blockDim.x + threadIdx.x) * 4;
  size_t gs = (size_t)gridDim.x * blockDim.x * 4;
  for (size_t j = i0; j < NIH; j += gs) {
    float4 v = *(const float4*)(wih + j);
    uint2 pk;
    pk.x = (unsigned)f2bf(v.x) | ((unsigned)f2bf(v.y) << 16);
    pk.y = (unsigned)f2bf(v.z) | ((unsigned)f2bf(v.w) << 16);
    *(uint2*)(oih + j) = pk;
  }
  for (size_t j = i0; j < NHH; j += gs) {
    float4 v = *(const float4*)(whh + j);
    uint2 pk;
    pk.x = (unsigned)f2bf(v.x) | ((unsigned)f2bf(v.y) << 16);
    pk.y = (unsigned)f2bf(v.z) | ((unsigned)f2bf(v.w) << 16);
    *(uint2*)(ohh + j) = pk;
  }
  if (oemb)
    for (size_t j = i0; j < NE; j += gs) {
      float4 v = *(const float4*)(wemb + j);
      uint2 pk;
      pk.x = (unsigned)f2bf(v.x) | ((unsigned)f2bf(v.y) << 16);
      pk.y = (unsigned)f2bf(v.z) | ((unsigned)f2bf(v.w) << 16);
      *(uint2*)(oemb + j) = pk;
    }
}

// ---------------- lengths / selection index ----------------
__global__ void k_tsel(const int* __restrict__ x, int* __restrict__ tsel,
                       int* __restrict__ padsel) {
  int b = threadIdx.x >> 3, j = threadIdx.x & 7;
  int c = 0;
  for (int t = j * 64; t < j * 64 + 64; ++t) c += (x[b * 512 + t] != 1) ? 1 : 0;
  c += __shfl_xor(c, 1);
  c += __shfl_xor(c, 2);
  c += __shfl_xor(c, 4);
  if (j == 0) {
    int ts = (c - 1) & 511;                        // len==0 wraps to T-1
    tsel[b] = ts;
    padsel[b] = (x[b * 512 + ts] == 1) ? 1 : 0;
  }
}

// ---------------- final logits: [64,1024] @ [8,1024]^T + b ----------------
__global__ void k_logits(const float* __restrict__ finalb, const float* __restrict__ Wout,
                         const float* __restrict__ bout, float* __restrict__ out) {
  int tid = threadIdx.x;
  for (int e = tid; e < 512; e += 256) {
    int b = e >> 3, o = e & 7;
    const float* f = finalb + (size_t)b * 1024;
    const float* w = Wout + (size_t)o * 1024;
    float s = 0.f;
    for (int k = 0; k < 1024; ++k) s += f[k] * w[k];
    out[e] = s + bout[o];
  }
}

// ---------------- main kernel: 256 wgs x 512 thr = 128 rec + 128 GEMM ----------------
// Rec: dual-chain (batch halves) wave pipelining; 2 waves/SIMD hide sync latency.
struct SmemT {
  unsigned tok[2];                                   // per-chain consumer token
  unsigned cnt[2];                                   // per-chain producer counter
  union {
    struct { unsigned short sW[32][1032]; } rec;     // W_hh slice, gate-interleaved rows
    struct { unsigned short A[128][72]; unsigned short Bt[256][72]; } g;
    struct { unsigned short zs[128][136]; } zst;
  } u;
  unsigned short pad_force_one_wg_per_cu[8192];      // -> ~82 KB: 1 wg/CU
};

__global__ __launch_bounds__(512, 1) void k_main(
    const int* __restrict__ x, const float* __restrict__ Wemb,
    const float* __restrict__ bih, const float* __restrict__ bhh,
    const unsigned short* __restrict__ Wihb, const unsigned short* __restrict__ Whhb,
    const unsigned short* __restrict__ wembb,
    unsigned short* __restrict__ hr, float* __restrict__ finalb,
    const int* __restrict__ tsel, const int* __restrict__ padsel,
    unsigned short* __restrict__ zxr, unsigned* __restrict__ bar, int chunkT,
    int nslot) {
  __shared__ SmemT smem;
  const int wg = blockIdx.x, tid = threadIdx.x;
  const int wave = tid >> 6, lane = tid & 63;
  const int l15 = lane & 15, lg = lane >> 4;
  unsigned* gemm_done = bar + 16640;
  const f32x4 fz = {0.f, 0.f, 0.f, 0.f};
  const int nChunks = 512 / chunkT;
  const size_t slotE = (size_t)chunkT * 64 * 4096;
  if (tid == 65535) smem.pad_force_one_wg_per_cu[0] = 0;

  if (wg < 128) {
    // ================= RECURRENT ROLE: dual chains =================
    const int chain = wave >> 2;        // 0: b 0..31, 1: b 32..63
    const int wv = wave & 3;            // role within chain
    const int btile = chain * 2 + (wv >> 1);
    const int mtile = wv & 1;
    const int my_b = btile * 16 + l15;
    const int col_local = 2 * lg + mtile;
    const int cg = wg * 8 + col_local;  // global h column
    unsigned* myflags = bar + chain * 8192;
    unsigned* recdone = bar + 16704 + chain * 64;

    if (tid == 0) { smem.tok[0] = 0; smem.tok[1] = 0; smem.cnt[0] = 0; smem.cnt[1] = 0; }
    // sW fill (512 threads): rows gate-interleaved as R14
    for (int e = tid; e < 32 * 64; e += 512) {
      int n = e >> 6, kq = (e & 63) << 4;
      int coll = (n < 16) ? 2 * (n >> 2) : 2 * ((n - 16) >> 2) + 1;
      int grow = (n & 3) * 1024 + wg * 8 + coll;
      *(uint4*)&smem.u.rec.sW[n][kq] = *(const uint4*)(Whhb + (size_t)grow * 1024 + kq);
      *(uint4*)&smem.u.rec.sW[n][kq + 8] =
          *(const uint4*)(Whhb + (size_t)grow * 1024 + kq + 8);
    }
    float biasv[4];
#pragma unroll
    for (int g = 0; g < 4; ++g) biasv[g] = bih[g * 1024 + cg] + bhh[g * 1024 + cg];
    const int my_tsel = tsel[my_b];
    const int my_pad = padsel[my_b];
    const size_t hwe = (size_t)btile * 16384 + (size_t)wg * 128 + (size_t)l15 * 8 + col_local;
    const size_t hre = (size_t)btile * 16384 + (size_t)lg * 128 + (size_t)l15 * 8;
    float cc = 0.f;

    // zero h slot 0 (128 KB total across wgs)
    {
      int e = wg * 512 + tid;
      if (e < 32768) AT_ST((unsigned*)hr + e, 0u, __ATOMIC_RELAXED);
    }
    __syncthreads();                    // drains all waves' stores; last wg-wide sync
    if (wv == 0 && lane == 0) AT_ST(myflags + wg * 64, 1u, __ATOMIC_RELAXED);

    for (int ch = 0; ch < nChunks; ++ch) {
      const int t0 = ch * chunkT;
      const unsigned short* zxbase = zxr + (size_t)(ch % nslot) * slotE;
      union { uint2 u2; unsigned short s[4]; } vv;
      bool vvload = true;               // load zx for tl=0 after chunk gate

      for (int tl = 0; tl < chunkT; ++tl) {
        const int t = t0 + tl;
        const unsigned need = (unsigned)t + 1u;

        if (wv == 0) {                  // chain poller wave
          if (tl == 0) {
            if (lane == 0) {
              while (AT_LD(gemm_done, __ATOMIC_RELAXED) < (unsigned)(ch + 1))
                __builtin_amdgcn_s_sleep(2);
              (void)AT_LD(gemm_done, __ATOMIC_ACQUIRE);   // inv: fresh zx + h-ring
              asm volatile("" ::: "memory");
            }
          }
          const unsigned* f0 = myflags + (lane * 2) * 64;
          const unsigned* f1 = myflags + (lane * 2 + 1) * 64;
          for (;;) {
            int ok = (AT_LD(f0, __ATOMIC_RELAXED) >= need) &&
                     (AT_LD(f1, __ATOMIC_RELAXED) >= need);
            if (__all(ok)) break;
            __builtin_amdgcn_s_sleep(1);
          }
          if (lane == 0) WG_ST(&smem.tok[chain], need);
        } else {
          while (WG_LD(&smem.tok[chain]) < need) __builtin_amdgcn_s_sleep(1);
        }
        asm volatile("" ::: "memory");

        if (vvload) {                   // zx for this step (post-acquire)
          vv.u2 = *(const uint2*)(zxbase + (size_t)(tl * 64 + my_b) * 4096 + cg * 4);
          vvload = false;
        }

        // ---- z = W_mtile @ h_btile : 32 MFMAs, K=1024 ----
        const unsigned short* hp = hr + (size_t)(t & 15) * HSLOT + hre;
        f32x4 r0 = fz;
        bf16x8 hf[32];
#pragma unroll
        for (int ks = 0; ks < 32; ++ks) hf[ks] = *(const bf16x8*)(hp + (size_t)ks * 512);
#pragma unroll
        for (int ks = 0; ks < 32; ++ks) {
          bf16x8 a0 = *(const bf16x8*)&smem.u.rec.sW[mtile * 16 + l15][ks * 32 + (lg << 3)];
          r0 = MFMA16(a0, hf[ks], r0);
        }

        // ---- gates lane-local: r0 = (i,f,g,o) for (my_b, cg) ----
        float z0 = r0[0] + biasv[0] + bf2f(vv.s[0]);
        float z1 = r0[1] + biasv[1] + bf2f(vv.s[1]);
        float z2 = r0[2] + biasv[2] + bf2f(vv.s[2]);
        float z3 = r0[3] + biasv[3] + bf2f(vv.s[3]);
        cc = sigf(z1) * cc + sigf(z0) * tanh_(z2);
        float h = sigf(z3) * tanh_(cc);

        if (t == my_tsel) finalb[(size_t)my_b * 1024 + cg] = my_pad ? 0.f : h;
        __hip_atomic_store(hr + (size_t)((t + 1) & 15) * HSLOT + hwe, f2bf(h),
                           __ATOMIC_RELAXED, __HIP_MEMORY_SCOPE_AGENT);

        asm volatile("s_waitcnt vmcnt(0)" ::: "memory");   // h (+finalb) store ack'd
        if (lane == 0)
          __hip_atomic_fetch_add(&smem.cnt[chain], 1u, __ATOMIC_ACQ_REL,
                                 __HIP_MEMORY_SCOPE_WORKGROUP);
        if (wv == 0 && lane == 0) {
          while (__hip_atomic_load(&smem.cnt[chain], __ATOMIC_ACQUIRE,
                                   __HIP_MEMORY_SCOPE_WORKGROUP) < 4u * need)
            __builtin_amdgcn_s_sleep(1);
          AT_ST(myflags + wg * 64, need + 1u, __ATOMIC_RELAXED);
        }

        if (tl + 1 < chunkT) {          // prefetch next step's zx — OFF the flag path
          vv.u2 = *(const uint2*)(zxbase + (size_t)((tl + 1) * 64 + my_b) * 4096 + cg * 4);
        }
      }
      if (wv == 0 && lane == 0) AT_ST(recdone, (unsigned)(ch + 1), __ATOMIC_RELAXED);
    }
  } else {
    // ============ GEMM ROLE (512 thr; tid&255 duplication — benign) ============
    const int gw = wg - 128;
    const int t2 = tid & 255;
    const int wv4 = (tid >> 6) & 3;
    unsigned* rdA = bar + 16704;
    unsigned* rdB = bar + 16768;
    unsigned gt = 0;
    for (int ch = 0; ch < nChunks; ++ch) {
      if (tid == 0 && ch >= nslot) {
        unsigned tgt = (unsigned)(ch - nslot + 1);
        for (;;) {
          unsigned a = AT_LD(rdA, __ATOMIC_RELAXED), b = AT_LD(rdB, __ATOMIC_RELAXED);
          if (a >= tgt && b >= tgt) break;
          __builtin_amdgcn_s_sleep(8);
        }
        asm volatile("" ::: "memory");
      }
      __syncthreads();
      const int t0 = ch * chunkT;
      unsigned short* zx = zxr + (size_t)(ch % nslot) * slotE;
      const int pmN = chunkT >> 1;
      const int npatch = pmN * 16;
      for (int p = gw; p < npatch; p += 128) {
        const int pm = p % pmN;
        const int n0 = (p / pmN) * 256;
        f32x4 acc[8][4];
#pragma unroll
        for (int mt = 0; mt < 8; ++mt)
#pragma unroll
          for (int nt = 0; nt < 4; ++nt) acc[mt][nt] = fz;
        for (int kc = 0; kc < 512; kc += 64) {
          __syncthreads();
          {
            int r = t2 >> 1, half = (t2 & 1) << 5;
            int tl = pm * 2 + (r >> 6), b = r & 63;
            int erow = x[b * 512 + t0 + tl];
            if (wembb) {
              const unsigned short* srcp = wembb + (size_t)erow * 512 + kc + half;
#pragma unroll
              for (int j = 0; j < 32; j += 8)
                *(uint4*)&smem.u.g.A[r][half + j] = *(const uint4*)(srcp + j);
            } else {
              const float* srcp = Wemb + (size_t)erow * 512 + kc + half;
#pragma unroll
              for (int j = 0; j < 32; j += 4) {
                float4 v = *(const float4*)(srcp + j);
                uint2 pk;
                pk.x = (unsigned)f2bf(v.x) | ((unsigned)f2bf(v.y) << 16);
                pk.y = (unsigned)f2bf(v.z) | ((unsigned)f2bf(v.w) << 16);
                *(uint2*)&smem.u.g.A[r][half + j] = pk;
              }
            }
          }
          {
            int zcx = n0 + t2;
            int wrow = (zcx & 3) * 1024 + (zcx >> 2);
            const unsigned short* srcp = Wihb + (size_t)wrow * 512 + kc;
#pragma unroll
            for (int j = 0; j < 64; j += 8)
              *(uint4*)&smem.u.g.Bt[t2][j] = *(const uint4*)(srcp + j);
          }
          __syncthreads();
#pragma unroll
          for (int ks = 0; ks < 64; ks += 32) {
            bf16x8 af[8];
#pragma unroll
            for (int mt = 0; mt < 8; ++mt)
              af[mt] = *(const bf16x8*)&smem.u.g.A[mt * 16 + l15][ks + (lg << 3)];
#pragma unroll
            for (int nt = 0; nt < 4; ++nt) {
              bf16x8 bfr =
                  *(const bf16x8*)&smem.u.g.Bt[(wv4 * 4 + nt) * 16 + l15][ks + (lg << 3)];
#pragma unroll
              for (int mt = 0; mt < 8; ++mt)
                acc[mt][nt] = MFMA16(af[mt], bfr, acc[mt][nt]);
            }
          }
        }
#pragma unroll
        for (int h = 0; h < 2; ++h) {
          __syncthreads();
          if ((wv4 >> 1) == h) {
#pragma unroll
            for (int mt = 0; mt < 8; ++mt)
#pragma unroll
              for (int nt = 0; nt < 4; ++nt)
#pragma unroll
                for (int r = 0; r < 4; ++r)
                  smem.u.zst.zs[mt * 16 + (lg << 2) + r][(wv4 & 1) * 64 + nt * 16 + l15] =
                      f2bf(acc[mt][nt][r]);
          }
          __syncthreads();
          int m = t2 >> 1, qq = (t2 & 1) << 6;
          int tl2 = pm * 2 + (m >> 6), bb = m & 63;
          unsigned short* dst = zx + ((size_t)(tl2 * 64 + bb)) * 4096 + n0 + h * 128 + qq;
#pragma unroll
          for (int j = 0; j < 64; j += 8)
            *(uint4*)(dst + j) = *(const uint4*)&smem.u.zst.zs[m][qq + j];
        }
      }
      gbar_gemm(bar, ++gt);
      if (wg == 128 && tid == 0) AT_ST(gemm_done, gt, __ATOMIC_RELAXED);
    }
  }
}

extern "C" void kernel_launch(void* const* d_in, const int* in_sizes, int n_in,
                              void* d_out, int out_size, void* d_ws, size_t ws_size,
                              hipStream_t stream) {
  (void)in_sizes; (void)n_in; (void)out_size;
  const int*   x    = (const int*)  d_in[0];
  const float* Wemb = (const float*)d_in[1];
  const float* Wih  = (const float*)d_in[2];
  const float* Whh  = (const float*)d_in[3];
  const float* bih  = (const float*)d_in[4];
  const float* bhh  = (const float*)d_in[5];
  const float* Wout = (const float*)d_in[6];
  const float* bout = (const float*)d_in[7];
  float* out = (float*)d_out;
  char* ws = (char*)d_ws;

  constexpr size_t OFF_WIH = 0;
  constexpr size_t OFF_WHH = OFF_WIH + (size_t)4096 * 512 * 2;    //  4 MB
  constexpr size_t OFF_HR  = OFF_WHH + (size_t)4096 * 1024 * 2;   // +8 MB
  constexpr size_t OFF_FIN = OFF_HR + (size_t)16 * HSLOT * 2;     // +2.06 MB
  constexpr size_t OFF_TS  = OFF_FIN + (size_t)64 * 1024 * 4;     // +256 KB
  constexpr size_t OFF_PS  = OFF_TS + 4096;
  constexpr size_t OFF_BAR = OFF_PS + 4096;
  constexpr size_t OFF_WEB = OFF_BAR + 73728;                     // 72 KB barrier zone
  constexpr size_t WEB_SZ  = (size_t)32000 * 512 * 2;             // 32 MB
  constexpr size_t SLOT_SZ = (size_t)16 * 64 * 4096 * 2;          // 8 MB per chunk slot

  int chunkT = 16;
  bool wbf = true;
  int nslot = 2;
  if (OFF_WEB + WEB_SZ + 2 * SLOT_SZ <= ws_size) {
    nslot = (int)((ws_size - OFF_WEB - WEB_SZ) / SLOT_SZ);
    if (nslot > 32) nslot = 32;
  } else if (OFF_WEB + 2 * SLOT_SZ <= ws_size) {
    wbf = false;
    nslot = (int)((ws_size - OFF_WEB) / SLOT_SZ);
    if (nslot > 32) nslot = 32;
  } else {
    wbf = false;
    while (chunkT > 2 &&
           OFF_WEB + (size_t)2 * chunkT * 64 * 4096 * 2 > ws_size)
      chunkT >>= 1;
  }
  const size_t OFF_ZX = OFF_WEB + (wbf ? WEB_SZ : 0);

  unsigned short* wihb  = (unsigned short*)(ws + OFF_WIH);
  unsigned short* whhb  = (unsigned short*)(ws + OFF_WHH);
  unsigned short* hr    = (unsigned short*)(ws + OFF_HR);
  float* finalb         = (float*)(ws + OFF_FIN);
  int* tsel             = (int*)(ws + OFF_TS);
  int* padsel           = (int*)(ws + OFF_PS);
  unsigned* bar         = (unsigned*)(ws + OFF_BAR);
  unsigned short* wembb = wbf ? (unsigned short*)(ws + OFF_WEB) : (unsigned short*)nullptr;
  unsigned short* zxr   = (unsigned short*)(ws + OFF_ZX);

  hipMemsetAsync(ws + OFF_BAR, 0, 73728, stream);
  k_conv<<<2048, 256, 0, stream>>>(Wih, Whh, Wemb, wihb, whhb, wembb);
  k_tsel<<<1, 512, 0, stream>>>(x, tsel, padsel);
  k_main<<<256, 512, 0, stream>>>(x, Wemb, bih, bhh, wihb, whhb, wembb, hr, finalb,
                                  tsel, padsel, zxr, bar, chunkT, nslot);
  k_logits<<<1, 256, 0, stream>>>(finalb, Wout, bout, out);
}